// Round 5
// baseline (766.848 us; speedup 1.0000x reference)
//
#include <hip/hip_runtime.h>
#include <hip/hip_cooperative_groups.h>
#include <math.h>

namespace cg = cooperative_groups;

#define EMB   4096
#define DIM   4096
#define TPREV 8192

// ws layout (floats):
//   [0,4096)      q
//   [4096,8192)   k
//   [8192,12288)  v
//   [12288,20481) a (8193)
//   [20544,...)   score partials part[128][8192] = 4 MB
#define WS_Q    0
#define WS_K    DIM
#define WS_V    (2*DIM)
#define WS_A    (3*DIM)
#define WS_PART 20544
#define NCHUNK      128
#define CHUNK_ROWS  32   // 4096 / 128

__device__ __forceinline__ float dot4(float4 a, float4 b) {
    return a.x * b.x + a.y * b.y + a.z * b.z + a.w * b.w;
}

//============================================================================
// Fused cooperative kernel: 1024 blocks x 256 threads = 4 blocks/CU (margin:
// launch_bounds(256,4) caps VGPR at 128, LDS 16KB -> 64KB/CU of 160KB).
//============================================================================
__global__ __launch_bounds__(256, 4) void fused_kernel(
    const float* __restrict__ x,
    const float* __restrict__ Wq, const float* __restrict__ Wk,
    const float* __restrict__ Wv,
    const float* __restrict__ Kc, const float* __restrict__ Vc,
    float* __restrict__ ws, float* __restrict__ out) {

    cg::grid_group grid = cg::this_grid();
    __shared__ __align__(16) float smem[4096];   // 16 KB
    float4* sm4 = (float4*)smem;

    const int tid  = threadIdx.x;
    const int lane = tid & 63;
    const int wave = tid >> 6;
    const int b    = blockIdx.x;

    //==================== Phase 1: q,k,v = W @ x ====================
    // 4096 waves; wave g owns row g of Wq, Wk, Wv (one full row each).
    {
        const float4* xg = (const float4*)x;     // stage x into LDS (16 KB)
        sm4[tid]       = xg[tid];
        sm4[tid + 256] = xg[tid + 256];
        sm4[tid + 512] = xg[tid + 512];
        sm4[tid + 768] = xg[tid + 768];
        __syncthreads();

        int gw = b * 4 + wave;                   // row 0..4095
        const float* Ws[3]  = {Wq, Wk, Wv};
        const int    off[3] = {WS_Q, WS_K, WS_V};
#pragma unroll
        for (int m = 0; m < 3; ++m) {
            const float4* row = (const float4*)(Ws[m] + (size_t)gw * EMB);
            float s = 0.f;
#pragma unroll
            for (int g = 0; g < 4; ++g) {        // 4 batches of 4 indep loads
                int base = g * 256 + lane;
                float4 w0 = row[base];
                float4 w1 = row[base + 64];
                float4 w2 = row[base + 128];
                float4 w3 = row[base + 192];
                s += dot4(w0, sm4[base])       + dot4(w1, sm4[base + 64])
                   + dot4(w2, sm4[base + 128]) + dot4(w3, sm4[base + 192]);
            }
#pragma unroll
            for (int o = 32; o > 0; o >>= 1) s += __shfl_down(s, o, 64);
            if (lane == 0) ws[off[m] + gw] = s;
        }
    }
    grid.sync();

    //==================== Phase 2: score partials ====================
    // b -> tt = b>>7 (t-tile of 1024), chunk = b&127 (32 rows of K_cache).
    // Thread owns 1 float4 of t; 8 groups of 4 independent row loads.
    {
        int tt    = b >> 7;
        int chunk = b & 127;
        if (tid < CHUNK_ROWS) smem[tid] = ws[WS_Q + chunk * CHUNK_ROWS + tid];
        __syncthreads();
        size_t t4 = (size_t)tt * 256 + tid;      // float4 idx in [0,2048)
        const float4* kc4 = (const float4*)Kc;
        float4 acc = {0.f, 0.f, 0.f, 0.f};
#pragma unroll
        for (int g = 0; g < CHUNK_ROWS / 4; ++g) {
            int r0 = chunk * CHUNK_ROWS + g * 4;
            float4 k0 = kc4[(size_t)(r0 + 0) * 2048 + t4];
            float4 k1 = kc4[(size_t)(r0 + 1) * 2048 + t4];
            float4 k2 = kc4[(size_t)(r0 + 2) * 2048 + t4];
            float4 k3 = kc4[(size_t)(r0 + 3) * 2048 + t4];
            float q0 = smem[g*4], q1 = smem[g*4+1], q2 = smem[g*4+2], q3 = smem[g*4+3];
            acc.x += q0 * k0.x + q1 * k1.x + q2 * k2.x + q3 * k3.x;
            acc.y += q0 * k0.y + q1 * k1.y + q2 * k2.y + q3 * k3.y;
            acc.z += q0 * k0.z + q1 * k1.z + q2 * k2.z + q3 * k3.z;
            acc.w += q0 * k0.w + q1 * k1.w + q2 * k2.w + q3 * k3.w;
        }
        ((float4*)(ws + WS_PART))[(size_t)chunk * 2048 + t4] = acc;
    }
    grid.sync();

    //==================== Phase 3: reduce 128 partials + sigmoid ====================
    if (b < 256) {
        // block owns 32 t (8 float4); 32 slices x 4 chunks each
        const float4* p4 = (const float4*)(ws + WS_PART);
        int f4    = tid & 7;
        int slice = tid >> 3;                    // 0..31
        size_t idx = (size_t)b * 8 + f4;
        float4 s = {0.f, 0.f, 0.f, 0.f};
#pragma unroll
        for (int c = 0; c < 4; ++c) {
            float4 v = p4[(size_t)(slice * 4 + c) * 2048 + idx];
            s.x += v.x; s.y += v.y; s.z += v.z; s.w += v.w;
        }
        sm4[tid] = s;
        __syncthreads();
        if (tid < 8) {
            float4 tot = {0.f, 0.f, 0.f, 0.f};
#pragma unroll
            for (int sl = 0; sl < 32; ++sl) {
                float4 v = sm4[sl * 8 + tid];
                tot.x += v.x; tot.y += v.y; tot.z += v.z; tot.w += v.w;
            }
            tot.x = 1.f / (1.f + __expf(-tot.x * 0.015625f));
            tot.y = 1.f / (1.f + __expf(-tot.y * 0.015625f));
            tot.z = 1.f / (1.f + __expf(-tot.z * 0.015625f));
            tot.w = 1.f / (1.f + __expf(-tot.w * 0.015625f));
            ((float4*)(ws + WS_A))[(size_t)b * 8 + tid] = tot;
        }
    } else if (b == 1023) {
        // tail: a[8192] = sigmoid(dot(q,k)/64)
        const float* q = ws + WS_Q;
        const float* k = ws + WS_K;
        float s = 0.f;
        int base = tid * 16;
#pragma unroll
        for (int i = 0; i < 16; ++i) s += q[base + i] * k[base + i];
        smem[tid] = s;
        __syncthreads();
        for (int o = 128; o > 0; o >>= 1) {
            if (tid < o) smem[tid] += smem[tid + o];
            __syncthreads();
        }
        if (tid == 0) ws[WS_A + TPREV] = 1.f / (1.f + __expf(-smem[0] * 0.015625f));
    }
    grid.sync();

    //==================== Phase 4: out = V @ a ====================
    // wave-per-row: 4096 waves, row = b*4+wave; 8 batches of 4+4 indep loads.
    {
        int r = b * 4 + wave;
        const float4* vrow = (const float4*)(Vc + (size_t)r * TPREV);
        const float4* a4   = (const float4*)(ws + WS_A);
        float s = 0.f;
#pragma unroll
        for (int g = 0; g < 8; ++g) {
            int base = g * 256 + lane;
            float4 v0 = vrow[base];
            float4 v1 = vrow[base + 64];
            float4 v2 = vrow[base + 128];
            float4 v3 = vrow[base + 192];
            float4 a0 = a4[base];
            float4 a1 = a4[base + 64];
            float4 a2 = a4[base + 128];
            float4 a3 = a4[base + 192];
            s += dot4(v0, a0) + dot4(v1, a1) + dot4(v2, a2) + dot4(v3, a3);
        }
#pragma unroll
        for (int o = 32; o > 0; o >>= 1) s += __shfl_down(s, o, 64);
        if (lane == 0)
            out[r] = s + ws[WS_V + r] * ws[WS_A + TPREV];
    }
}

//============================================================================
// Fallback path: the verified R3 four-kernel pipeline (used only if the
// cooperative launch is rejected).
//============================================================================
__global__ __launch_bounds__(256) void qkv_kernel(
    const float* __restrict__ x,
    const float* __restrict__ Wq, const float* __restrict__ Wk,
    const float* __restrict__ Wv, float* __restrict__ ws) {
    int b = blockIdx.x;
    int m = b >> 12;
    int r = b & 4095;
    const float* W = (m == 0) ? Wq : (m == 1) ? Wk : Wv;
    const float4* row = (const float4*)(W + (size_t)r * EMB);
    const float4* xv  = (const float4*)x;
    int tid = threadIdx.x;

    float4 w0 = row[tid];
    float4 w1 = row[tid + 256];
    float4 w2 = row[tid + 512];
    float4 w3 = row[tid + 768];
    float4 x0 = xv[tid];
    float4 x1 = xv[tid + 256];
    float4 x2 = xv[tid + 512];
    float4 x3 = xv[tid + 768];

    float s = dot4(w0, x0) + dot4(w1, x1) + dot4(w2, x2) + dot4(w3, x3);
#pragma unroll
    for (int off = 32; off > 0; off >>= 1) s += __shfl_down(s, off, 64);
    __shared__ float red[4];
    if ((tid & 63) == 0) red[tid >> 6] = s;
    __syncthreads();
    if (tid == 0) ws[m * DIM + r] = red[0] + red[1] + red[2] + red[3];
}

__global__ __launch_bounds__(256) void score_kernel(
    const float* __restrict__ Kc, float* __restrict__ ws) {
    const float* q = ws + WS_Q;
    float* part    = ws + WS_PART;

    __shared__ float qs[CHUNK_ROWS];
    int d0 = blockIdx.y * CHUNK_ROWS;
    if (threadIdx.x < CHUNK_ROWS) qs[threadIdx.x] = q[d0 + threadIdx.x];
    __syncthreads();

    size_t t = (size_t)blockIdx.x * 1024 + threadIdx.x * 4;
    const float* base = Kc + (size_t)d0 * TPREV + t;
    float4 acc = {0.f, 0.f, 0.f, 0.f};
#pragma unroll
    for (int g = 0; g < CHUNK_ROWS / 4; ++g) {
        float4 k0 = *(const float4*)(base + (size_t)(4 * g + 0) * TPREV);
        float4 k1 = *(const float4*)(base + (size_t)(4 * g + 1) * TPREV);
        float4 k2 = *(const float4*)(base + (size_t)(4 * g + 2) * TPREV);
        float4 k3 = *(const float4*)(base + (size_t)(4 * g + 3) * TPREV);
        float q0 = qs[4 * g], q1 = qs[4 * g + 1], q2 = qs[4 * g + 2], q3 = qs[4 * g + 3];
        acc.x += q0 * k0.x + q1 * k1.x + q2 * k2.x + q3 * k3.x;
        acc.y += q0 * k0.y + q1 * k1.y + q2 * k2.y + q3 * k3.y;
        acc.z += q0 * k0.z + q1 * k1.z + q2 * k2.z + q3 * k3.z;
        acc.w += q0 * k0.w + q1 * k1.w + q2 * k2.w + q3 * k3.w;
    }
    *(float4*)(part + (size_t)blockIdx.y * TPREV + t) = acc;
}

__global__ __launch_bounds__(256) void reduce_sigmoid_kernel(
    float* __restrict__ ws) {
    if (blockIdx.x < 64) {
        const float4* p = (const float4*)(ws + WS_PART);
        int f4    = threadIdx.x & 31;
        int slice = threadIdx.x >> 5;
        size_t idx = (size_t)(slice * 16) * (TPREV / 4) + (size_t)blockIdx.x * 32 + f4;
        float4 s = {0.f, 0.f, 0.f, 0.f};
#pragma unroll 4
        for (int c = 0; c < 16; ++c) {
            float4 v = p[idx + (size_t)c * (TPREV / 4)];
            s.x += v.x; s.y += v.y; s.z += v.z; s.w += v.w;
        }
        __shared__ float4 red[256];
        red[threadIdx.x] = s;
        __syncthreads();
        if (threadIdx.x < 32) {
            float4 tot = red[threadIdx.x];
#pragma unroll
            for (int sl = 1; sl < 8; ++sl) {
                float4 v = red[sl * 32 + threadIdx.x];
                tot.x += v.x; tot.y += v.y; tot.z += v.z; tot.w += v.w;
            }
            tot.x = 1.0f / (1.0f + __expf(-tot.x * 0.015625f));
            tot.y = 1.0f / (1.0f + __expf(-tot.y * 0.015625f));
            tot.z = 1.0f / (1.0f + __expf(-tot.z * 0.015625f));
            tot.w = 1.0f / (1.0f + __expf(-tot.w * 0.015625f));
            ((float4*)(ws + WS_A))[(size_t)blockIdx.x * 32 + threadIdx.x] = tot;
        }
    } else {
        const float* q = ws + WS_Q;
        const float* k = ws + WS_K;
        float s = 0.0f;
        int base = threadIdx.x * 16;
#pragma unroll
        for (int i = 0; i < 16; ++i) s += q[base + i] * k[base + i];
        __shared__ float red[256];
        red[threadIdx.x] = s;
        __syncthreads();
        for (int off = 128; off > 0; off >>= 1) {
            if (threadIdx.x < off) red[threadIdx.x] += red[threadIdx.x + off];
            __syncthreads();
        }
        if (threadIdx.x == 0) {
            float v = red[0] * 0.015625f;
            ws[WS_A + TPREV] = 1.0f / (1.0f + __expf(-v));
        }
    }
}

__global__ __launch_bounds__(256) void out_kernel(
    const float* __restrict__ Vc, const float* __restrict__ ws,
    float* __restrict__ out) {
    int d = blockIdx.x;
    const float4* row = (const float4*)(Vc + (size_t)d * TPREV);
    const float4* av  = (const float4*)(ws + WS_A);
    int tid = threadIdx.x;
    float s = 0.0f;
#pragma unroll
    for (int g = 0; g < 2; ++g) {
        int o = g * 1024;
        float4 v0 = row[o + tid];
        float4 v1 = row[o + tid + 256];
        float4 v2 = row[o + tid + 512];
        float4 v3 = row[o + tid + 768];
        float4 a0 = av[o + tid];
        float4 a1 = av[o + tid + 256];
        float4 a2 = av[o + tid + 512];
        float4 a3 = av[o + tid + 768];
        s += dot4(v0, a0) + dot4(v1, a1) + dot4(v2, a2) + dot4(v3, a3);
    }
#pragma unroll
    for (int off = 32; off > 0; off >>= 1) s += __shfl_down(s, off, 64);
    __shared__ float red[4];
    if ((tid & 63) == 0) red[tid >> 6] = s;
    __syncthreads();
    if (tid == 0)
        out[d] = red[0] + red[1] + red[2] + red[3]
               + ws[WS_V + d] * ws[WS_A + TPREV];
}

// ---------------------------------------------------------------------------
extern "C" void kernel_launch(void* const* d_in, const int* in_sizes, int n_in,
                              void* d_out, int out_size, void* d_ws, size_t ws_size,
                              hipStream_t stream) {
    const float* x  = (const float*)d_in[0];
    const float* Wq = (const float*)d_in[1];
    const float* Wk = (const float*)d_in[2];
    const float* Wv = (const float*)d_in[3];
    const float* Kc = (const float*)d_in[4];
    const float* Vc = (const float*)d_in[5];
    float* out = (float*)d_out;
    float* ws  = (float*)d_ws;

    void* args[] = {(void*)&x, (void*)&Wq, (void*)&Wk, (void*)&Wv,
                    (void*)&Kc, (void*)&Vc, (void*)&ws, (void*)&out};
    hipError_t err = hipLaunchCooperativeKernel((void*)fused_kernel, dim3(1024),
                                                dim3(256), args, 0, stream);
    if (err != hipSuccess) {
        // deterministic fallback: verified 4-kernel pipeline
        qkv_kernel<<<12288, 256, 0, stream>>>(x, Wq, Wk, Wv, ws);
        score_kernel<<<dim3(8, 128), 256, 0, stream>>>(Kc, ws);
        reduce_sigmoid_kernel<<<65, 256, 0, stream>>>(ws);
        out_kernel<<<4096, 256, 0, stream>>>(Vc, ws, out);
    }
}